// Round 7
// baseline (578.888 us; speedup 1.0000x reference)
//
#include <hip/hip_runtime.h>
#include <stdint.h>

// Problem constants (CrossAttentionLayer: B=8, NQ=64, S=4096, D=1024, H=16, HD=64)
#define BATCH   8
#define NQL     64
#define SLEN    4096
#define DMODEL  1024
#define NHEADS  16
#define HDIM    64
#define NSPLIT  8          // S-splits for attention (each split = 512 positions = 8 tiles)

typedef float          f32x4  __attribute__((ext_vector_type(4)));
typedef __bf16         bf16x8 __attribute__((ext_vector_type(8)));
typedef unsigned int   u32x4  __attribute__((ext_vector_type(4)));
typedef unsigned short u16x4  __attribute__((ext_vector_type(4)));
typedef unsigned short u16x8  __attribute__((ext_vector_type(8)));

__device__ __forceinline__ unsigned short f2bf(float f) {
  unsigned int u = __builtin_bit_cast(unsigned int, f);
  u += 0x7FFFu + ((u >> 16) & 1u);          // RTNE
  return (unsigned short)(u >> 16);
}

__device__ __forceinline__ f32x4 mfma16(bf16x8 a, bf16x8 b, f32x4 c) {
  return __builtin_amdgcn_mfma_f32_16x16x32_bf16(a, b, c, 0, 0, 0);
}

__device__ __forceinline__ bf16x8 lds_frag(const char* p) {
  u32x4 v = *(const u32x4*)p;               // ds_read_b128
  return __builtin_bit_cast(bf16x8, v);
}

__device__ __forceinline__ void gload_lds16(const void* g, void* l) {
  // async global->LDS, 16B per lane; LDS dest = wave-uniform base + lane*16
  __builtin_amdgcn_global_load_lds((const __attribute__((address_space(1))) void*)g,
                                   (__attribute__((address_space(3))) void*)l, 16, 0, 0);
}

// ----------------------------- fused fp32 -> bf16 convert (grid-stride, 1 launch) -------------
// segment prefix sums in n8 units:
//   ctx 4194304 | q 65536 | wq/wk/wv/wo 131072 each ; total 4784128
// Also zeroes the 128 attn per-bh combine counters (block 0).
#define CVT_TOT   4784128
#define CVT_STEP  (2048 * 256)
__global__ __launch_bounds__(256)
void cvt6_kernel(const float* __restrict__ p0, const float* __restrict__ p1,
                 const float* __restrict__ p2, const float* __restrict__ p3,
                 const float* __restrict__ p4, const float* __restrict__ p5,
                 unsigned short* __restrict__ o0, unsigned short* __restrict__ o1,
                 unsigned short* __restrict__ o2, unsigned short* __restrict__ o3,
                 unsigned short* __restrict__ o4, unsigned short* __restrict__ o5,
                 unsigned int* __restrict__ cnt) {
  if (blockIdx.x == 0 && threadIdx.x < BATCH * NHEADS) cnt[threadIdx.x] = 0u;
  for (int i = blockIdx.x * 256 + threadIdx.x; i < CVT_TOT; i += CVT_STEP) {
    const float* src; unsigned short* dst; int rel;
    if      (i < 4194304) { src = p0; dst = o0; rel = i; }
    else if (i < 4259840) { src = p1; dst = o1; rel = i - 4194304; }
    else if (i < 4390912) { src = p2; dst = o2; rel = i - 4259840; }
    else if (i < 4521984) { src = p3; dst = o3; rel = i - 4390912; }
    else if (i < 4653056) { src = p4; dst = o4; rel = i - 4521984; }
    else                  { src = p5; dst = o5; rel = i - 4653056; }
    const float4* p = (const float4*)src + (size_t)rel * 2;
    float4 a = p[0], b = p[1];
    u16x8 o;
    o[0] = f2bf(a.x); o[1] = f2bf(a.y); o[2] = f2bf(a.z); o[3] = f2bf(a.w);
    o[4] = f2bf(b.x); o[5] = f2bf(b.y); o[6] = f2bf(b.z); o[7] = f2bf(b.w);
    *((u16x8*)dst + rel) = o;
  }
}

// ----------------------------- 128x128 GEMM body (m97 single-buffer, XCD-chunked) -------------
// C = A (Mx1024) * B (1024x1024)^T + bias.  4 waves (2x2), per-wave 64x64, 16x16x32
// MFMA, BK=64, single-buffered 32KB LDS -> ~5 blocks/CU (20 waves/CU cross-block
// overlap; m97/m103-verified structure ~900 TF).  XCD-chunked swizzle (proven R6:
// FETCH = A read once, conflicts 0).  MODE 0: bf16 out [M][1024].  MODE 1: fp32 out.
// MODE 2: bf16 transposed V layout Vt[((r>>12)*1024 + c)*4096 + (r&4095)].
template<int MODE>
__device__ __forceinline__
void gemm_body(char* lds, const unsigned short* __restrict__ A,
               const unsigned short* __restrict__ Bw, const float* __restrict__ bias,
               void* __restrict__ Cout, int M, int lb) {
  const int K = 1024, N = 1024;
  const int tid  = threadIdx.x;
  const int wave = tid >> 6, lane = tid & 63;
  const int g    = lane >> 4, ln = lane & 15;

  // XCD-chunked bijective swizzle within this segment (nwg % 8 == 0 always here)
  const int nwg = (M >> 7) << 3;            // (M/128) * (N/128), N=1024
  const int cpx = nwg >> 3;
  const int wg  = (lb & 7) * cpx + (lb >> 3);
  const int brow = (wg >> 3) << 7;          // nbn = 8
  const int bcol = (wg & 7) << 7;
  const int wr   = wave >> 1, wc = wave & 1;

  f32x4 acc[4][4];
#pragma unroll
  for (int i = 0; i < 4; ++i)
#pragma unroll
    for (int j = 0; j < 4; ++j) acc[i][j] = (f32x4){0.f, 0.f, 0.f, 0.f};

  const int srow = lane >> 3;
  const int srcs = (lane & 7) ^ (srow & 7);

  for (int kt = 0; kt < 16; ++kt) {
    // ---- stage A,B tiles (16KB each = 16 chunks of 1KB; 4 chunks/wave each) ----
#pragma unroll
    for (int c = wave; c < 16; c += 4) {
      int row = (c << 3) + srow;
      gload_lds16(A + (size_t)(brow + row) * K + (kt << 6) + (srcs << 3), lds + (c << 10));
      gload_lds16(Bw + (size_t)(bcol + row) * K + (kt << 6) + (srcs << 3), lds + 16384 + (c << 10));
    }
    __syncthreads();                        // compiler drains vmcnt(0) before barrier

#pragma unroll
    for (int ks = 0; ks < 2; ++ks) {
      bf16x8 af[4], bfr[4];
      const int slot = ((ks << 2) + g) ^ (ln & 7);
#pragma unroll
      for (int mt = 0; mt < 4; ++mt) {
        int row = wr * 64 + mt * 16 + ln;
        af[mt] = lds_frag(lds + row * 128 + (slot << 4));
      }
#pragma unroll
      for (int nt = 0; nt < 4; ++nt) {
        int row = wc * 64 + nt * 16 + ln;
        bfr[nt] = lds_frag(lds + 16384 + row * 128 + (slot << 4));
      }
      __builtin_amdgcn_s_setprio(1);
#pragma unroll
      for (int mt = 0; mt < 4; ++mt)
#pragma unroll
        for (int nt = 0; nt < 4; ++nt)
          acc[mt][nt] = mfma16(af[mt], bfr[nt], acc[mt][nt]);
      __builtin_amdgcn_s_setprio(0);
    }
    __syncthreads();                        // all reads done before next stage
  }

#pragma unroll
  for (int mt = 0; mt < 4; ++mt) {
#pragma unroll
    for (int nt = 0; nt < 4; ++nt) {
      f32x4 v = acc[mt][nt];
      int r0 = brow + wr * 64 + mt * 16 + g * 4;
      int c  = bcol + wc * 64 + nt * 16 + ln;
      float bi = bias[c];
      if constexpr (MODE == 0) {
        unsigned short* Cb = (unsigned short*)Cout;
#pragma unroll
        for (int j = 0; j < 4; ++j) Cb[(size_t)(r0 + j) * N + c] = f2bf(v[j] + bi);
      } else if constexpr (MODE == 1) {
        float* Cf = (float*)Cout;
#pragma unroll
        for (int j = 0; j < 4; ++j) Cf[(size_t)(r0 + j) * N + c] = v[j] + bi;
      } else {
        u16x4 pk;
#pragma unroll
        for (int j = 0; j < 4; ++j) pk[j] = f2bf(v[j] + bi);
        size_t base = ((size_t)(r0 >> 12) * 1024 + c) * 4096 + (size_t)(r0 & 4095);
        *(u16x4*)((unsigned short*)Cout + base) = pk;
      }
    }
  }
}

// ----------------------------- mega projection kernel: K + V + Q in one launch ----------------
// blocks [0,2048) K-proj | [2048,4096) V-proj (transposed Vt out) | [4096,4128) Q-proj
__global__ __launch_bounds__(256)
void proj3_kernel(const unsigned short* __restrict__ ctx_bf, const unsigned short* __restrict__ q_bf,
                  const unsigned short* __restrict__ wk_bf, const unsigned short* __restrict__ wv_bf,
                  const unsigned short* __restrict__ wq_bf,
                  const float* __restrict__ bk, const float* __restrict__ bv,
                  const float* __restrict__ bq,
                  unsigned short* __restrict__ Kp, unsigned short* __restrict__ Vt,
                  unsigned short* __restrict__ Qp) {
  __shared__ char lds[32768];
  const int bid = (int)blockIdx.x;
  if (bid < 2048)       gemm_body<0>(lds, ctx_bf, wk_bf, bk, Kp, BATCH * SLEN, bid);
  else if (bid < 4096)  gemm_body<2>(lds, ctx_bf, wv_bf, bv, Vt, BATCH * SLEN, bid - 2048);
  else                  gemm_body<0>(lds, q_bf, wq_bf, bq, Qp, BATCH * NQL, bid - 4096);
}

// ----------------------------- output projection -----------------------------
__global__ __launch_bounds__(256)
void gemm_o_kernel(const unsigned short* __restrict__ Ao, const unsigned short* __restrict__ wo_bf,
                   const float* __restrict__ bo, float* __restrict__ out) {
  __shared__ char lds[32768];
  gemm_body<1>(lds, Ao, wo_bf, bo, out, BATCH * NQL, (int)blockIdx.x);
}

// ----------------------------- split-S flash attention + fused combine ------------------------
// grid = B*H*NSPLIT.  Each block: 64 q rows x 512 s positions.  Partials to Opart/
// Mpart/Lpart; per-bh the LAST finishing block (device-scope acq_rel counter)
// combines all NSPLIT partials and writes Ao directly (flash-decode pattern).
__global__ __launch_bounds__(256)
void attn_split(const unsigned short* __restrict__ Qp,  // [B*NQ][1024]
                const unsigned short* __restrict__ Kp,  // [B*S][1024]
                const unsigned short* __restrict__ Vt,  // [b*1024 + h*64 + hd][4096]
                float* __restrict__ Opart,              // [(sp*128+bh)*64 + q][64]
                float* __restrict__ Mpart,              // [(sp*128+bh)*64 + q]
                float* __restrict__ Lpart,
                unsigned int* __restrict__ cnt,         // [128] zeroed by cvt6
                unsigned short* __restrict__ Aout) {    // [B*NQ][1024]
  __shared__ char ldsKV[2][16384];                       // [buf][ K 8KB | V 8KB ]
  __shared__ unsigned int plds[4 * 16 * 36];
  __shared__ unsigned int lastflag;

  const int bh = (int)blockIdx.x / NSPLIT;
  const int sp = (int)blockIdx.x % NSPLIT;
  const int b = bh >> 4, h = bh & 15;
  const int tid = threadIdx.x;
  const int wave = tid >> 6, lane = tid & 63;
  const int g = lane >> 4, ln = lane & 15;
  const int pbase = wave * 576 + ln * 36;
  const int srow = lane >> 3;
  const int srcs = (lane & 7) ^ (srow & 7);

  const unsigned short* qb =
      Qp + ((size_t)(b * 64 + wave * 16 + ln) * 1024) + h * 64 + g * 8;
  bf16x8 qf[2];
  qf[0] = __builtin_bit_cast(bf16x8, *(const u32x4*)qb);
  qf[1] = __builtin_bit_cast(bf16x8, *(const u32x4*)(qb + 32));

  f32x4 oacc[4];
#pragma unroll
  for (int i = 0; i < 4; ++i) oacc[i] = (f32x4){0.f, 0.f, 0.f, 0.f};
  float mrun = -1e30f, lrun = 0.f;

  auto stage = [&](int t, int buf) {        // t = GLOBAL tile index (0..63)
    int s0 = t << 6;
    char* bK = ldsKV[buf];
#pragma unroll
    for (int c4 = 0; c4 < 4; ++c4) {
      int c = wave * 4 + c4;
      int cc = c & 7;
      int row = (cc << 3) + srow;
      const char* gsrc;
      if (c < 8)
        gsrc = (const char*)Kp + (((size_t)((b << 12) + s0 + row) * 1024 + (h << 6) + (srcs << 3)) << 1);
      else
        gsrc = (const char*)Vt + (((size_t)((b << 10) + (h << 6) + row) * 4096 + s0 + (srcs << 3)) << 1);
      gload_lds16(gsrc, bK + ((c < 8) ? 0 : 8192) + (cc << 10));
    }
  };

  const int T0 = sp * (SLEN / 64 / NSPLIT);              // 8 tiles per split
  const int NTL = SLEN / 64 / NSPLIT;
  stage(T0, 0);
  for (int tl = 0; tl < NTL; ++tl) {
    asm volatile("s_waitcnt vmcnt(0)" ::: "memory");
    __syncthreads();
    if (tl + 1 < NTL) stage(T0 + tl + 1, (tl + 1) & 1);

    char* bufK = ldsKV[tl & 1];
    char* bufV = bufK + 8192;

    f32x4 s4[4];
#pragma unroll
    for (int i = 0; i < 4; ++i) s4[i] = (f32x4){0.f, 0.f, 0.f, 0.f};
    __builtin_amdgcn_s_setprio(1);
#pragma unroll
    for (int ks = 0; ks < 2; ++ks) {
      const int slot = ((ks << 2) + g) ^ (ln & 7);
#pragma unroll
      for (int mt = 0; mt < 4; ++mt) {
        int row = mt * 16 + ln;
        s4[mt] = mfma16(lds_frag(bufK + row * 128 + (slot << 4)), qf[ks], s4[mt]);
      }
    }
    __builtin_amdgcn_s_setprio(0);

    float tmax = -1e30f;
#pragma unroll
    for (int mt = 0; mt < 4; ++mt)
#pragma unroll
      for (int j = 0; j < 4; ++j) {
        float sv = s4[mt][j] * 0.125f;
        s4[mt][j] = sv;
        tmax = fmaxf(tmax, sv);
      }
    tmax = fmaxf(tmax, __shfl_xor(tmax, 16));
    tmax = fmaxf(tmax, __shfl_xor(tmax, 32));
    float mnew = fmaxf(mrun, tmax);
    float factor = __expf(mrun - mnew);
    float psum = 0.f;
#pragma unroll
    for (int mt = 0; mt < 4; ++mt) {
      float p0 = __expf(s4[mt][0] - mnew);
      float p1 = __expf(s4[mt][1] - mnew);
      float p2 = __expf(s4[mt][2] - mnew);
      float p3 = __expf(s4[mt][3] - mnew);
      psum += (p0 + p1) + (p2 + p3);
      plds[pbase + mt * 8 + g * 2 + 0] = (unsigned)f2bf(p0) | ((unsigned)f2bf(p1) << 16);
      plds[pbase + mt * 8 + g * 2 + 1] = (unsigned)f2bf(p2) | ((unsigned)f2bf(p3) << 16);
    }
    psum += __shfl_xor(psum, 16);
    psum += __shfl_xor(psum, 32);
    lrun = lrun * factor + psum;
    mrun = mnew;

    float fj0 = __shfl(factor, g * 4 + 0);
    float fj1 = __shfl(factor, g * 4 + 1);
    float fj2 = __shfl(factor, g * 4 + 2);
    float fj3 = __shfl(factor, g * 4 + 3);
#pragma unroll
    for (int nt = 0; nt < 4; ++nt) {
      oacc[nt][0] *= fj0; oacc[nt][1] *= fj1; oacc[nt][2] *= fj2; oacc[nt][3] *= fj3;
    }

    __builtin_amdgcn_s_setprio(1);
#pragma unroll
    for (int kt2 = 0; kt2 < 2; ++kt2) {
      u32x4 pv;
      int pidx = pbase + kt2 * 16 + g * 4;
      pv[0] = plds[pidx]; pv[1] = plds[pidx + 1]; pv[2] = plds[pidx + 2]; pv[3] = plds[pidx + 3];
      bf16x8 pa = __builtin_bit_cast(bf16x8, pv);
      const int slot = ((kt2 << 2) + g) ^ (ln & 7);
#pragma unroll
      for (int nt = 0; nt < 4; ++nt) {
        int row = nt * 16 + ln;
        oacc[nt] = mfma16(pa, lds_frag(bufV + row * 128 + (slot << 4)), oacc[nt]);
      }
    }
    __builtin_amdgcn_s_setprio(0);
  }

  // ---- store UNNORMALIZED partial O + m,l ----
  const int rowb = sp * (BATCH * NHEADS * 64) + bh * 64;   // sp*8192 + bh*64
#pragma unroll
  for (int nt = 0; nt < 4; ++nt) {
#pragma unroll
    for (int j = 0; j < 4; ++j) {
      int q = wave * 16 + g * 4 + j;
      Opart[(size_t)(rowb + q) * 64 + nt * 16 + ln] = oacc[nt][j];
    }
  }
  if (g == 0) {
    Mpart[rowb + wave * 16 + ln] = mrun;
    Lpart[rowb + wave * 16 + ln] = lrun;
  }

  // ---- fused combine: last block per bh merges all NSPLIT partials ----
  __threadfence();                          // make this block's stores device-visible
  __syncthreads();
  if (tid == 0) {
    unsigned int prev = __hip_atomic_fetch_add(&cnt[bh], 1u, __ATOMIC_ACQ_REL,
                                               __HIP_MEMORY_SCOPE_AGENT);
    lastflag = (prev == NSPLIT - 1) ? 1u : 0u;
  }
  __syncthreads();
  if (lastflag) {
    const int hd = tid & 63;
    const int q0 = (tid >> 6) << 4;         // 0,16,32,48
    for (int qq = 0; qq < 16; ++qq) {
      const int q = q0 + qq;
      const int row = bh * 64 + q;
      float mi[NSPLIT];
      float Mx = -1e30f;
#pragma unroll
      for (int i = 0; i < NSPLIT; ++i) {
        mi[i] = Mpart[i * 8192 + row];
        Mx = fmaxf(Mx, mi[i]);
      }
      float L = 0.f, o = 0.f;
#pragma unroll
      for (int i = 0; i < NSPLIT; ++i) {
        float w = __expf(mi[i] - Mx);
        L += Lpart[i * 8192 + row] * w;
        o += Opart[(size_t)(i * 8192 + row) * 64 + hd] * w;
      }
      Aout[(size_t)(b * 64 + q) * 1024 + h * 64 + hd] = f2bf(o / L);
    }
  }
}

// ----------------------------- launch -----------------------------
extern "C" void kernel_launch(void* const* d_in, const int* in_sizes, int n_in,
                              void* d_out, int out_size, void* d_ws, size_t ws_size,
                              hipStream_t stream) {
  const float* queries = (const float*)d_in[0];
  const float* context = (const float*)d_in[1];
  const float* wq = (const float*)d_in[2];
  const float* bq = (const float*)d_in[3];
  const float* wk = (const float*)d_in[4];
  const float* bk = (const float*)d_in[5];
  const float* wv = (const float*)d_in[6];
  const float* bv = (const float*)d_in[7];
  const float* wo = (const float*)d_in[8];
  const float* bo = (const float*)d_in[9];

  const size_t CTX_E = (size_t)BATCH * SLEN * DMODEL;   // 33,554,432
  const size_t QRY_E = (size_t)BATCH * NQL * DMODEL;    // 524,288
  const size_t W_E   = (size_t)DMODEL * DMODEL;         // 1,048,576

  char* ws = (char*)d_ws;
  size_t off = 0;
  auto alloc = [&](size_t bytes) {
    char* p = ws + off;
    off += (bytes + 255) & ~(size_t)255;
    return p;
  };
  unsigned short* ctx_bf = (unsigned short*)alloc(CTX_E * 2);
  unsigned short* q_bf   = (unsigned short*)alloc(QRY_E * 2);
  unsigned short* wq_bf  = (unsigned short*)alloc(W_E * 2);
  unsigned short* wk_bf  = (unsigned short*)alloc(W_E * 2);
  unsigned short* wv_bf  = (unsigned short*)alloc(W_E * 2);
  unsigned short* wo_bf  = (unsigned short*)alloc(W_E * 2);
  unsigned short* Qp     = (unsigned short*)alloc(QRY_E * 2);
  unsigned short* Kp     = (unsigned short*)alloc(CTX_E * 2);
  unsigned short* Vt     = (unsigned short*)alloc(CTX_E * 2);
  unsigned short* Ao     = (unsigned short*)alloc(QRY_E * 2);
  unsigned int*   cnt    = (unsigned int*)alloc(BATCH * NHEADS * sizeof(unsigned int));
  if (off > ws_size) return;

  // attention partials ALIAS ctx_bf (dead after proj3):
  // Opart 16.78MB + Mpart 256KB + Lpart 256KB  <  67MB
  float* Opart = (float*)ctx_bf;
  float* Mpart = Opart + (size_t)NSPLIT * BATCH * NHEADS * 64 * 64;
  float* Lpart = Mpart + (size_t)NSPLIT * BATCH * NHEADS * 64;

  // 1) fused convert (grid-stride) + counter zeroing
  cvt6_kernel<<<dim3(2048), 256, 0, stream>>>(context, queries, wq, wk, wv, wo,
                                              ctx_bf, q_bf, wq_bf, wk_bf, wv_bf, wo_bf, cnt);

  // 2) all three projections in ONE launch (K 2048 | V 2048 | Q 32 blocks)
  proj3_kernel<<<dim3(4128), 256, 0, stream>>>(ctx_bf, q_bf, wk_bf, wv_bf, wq_bf,
                                               bk, bv, bq, Kp, Vt, Qp);

  // 3) split-S attention with fused last-block combine
  attn_split<<<dim3(BATCH * NHEADS * NSPLIT), 256, 0, stream>>>(Qp, Kp, Vt, Opart, Mpart,
                                                                Lpart, cnt, Ao);

  // 4) output projection (fp32 out)
  gemm_o_kernel<<<dim3(32), 256, 0, stream>>>(Ao, wo_bf, bo, (float*)d_out);
}